// Round 5
// baseline (262.641 us; speedup 1.0000x reference)
//
#include <hip/hip_runtime.h>
#include <hip/hip_bf16.h>

#define GSZ 36
static const int NX  = 16 * 32 * 224 * 224;     // 25,690,112
static const int NX4 = NX / 4;                  // 6,422,528 (NX % 4 == 0)
static const int NW  = 32 * 32 * 3 * 3;         // 9,216
static const int GXN = (NX + GSZ - 1) / GSZ;    // 713,615
static const int HWp = 224 * 224;               // 50,176

typedef short bf16x8 __attribute__((ext_vector_type(8)));
typedef float f32x4  __attribute__((ext_vector_type(4)));

// floor(n/36), exact for n < 2^31
__device__ __forceinline__ unsigned div36(unsigned n) {
    return (unsigned)(((unsigned long long)n * 954437177ull) >> 35);
}
// scale = 2^(floor(log2 m) - 7) via exponent field (m normal > 0)
__device__ __forceinline__ float scale_from_max(float m) {
    int e = (int)((__float_as_uint(m) >> 23) & 0xffu) - 127;
    return __uint_as_float((unsigned)(e + 120) << 23);
}
// 1/scale for power-of-two scale: bits = 0x7F000000 - scale_bits
__device__ __forceinline__ float inv_from_scale(float s) {
    return __uint_as_float(0x7F000000u - __float_as_uint(s));
}
__device__ __forceinline__ unsigned short f2bf(float f) {
    return (unsigned short)(__float_as_uint(f) >> 16);  // exact for BFP-8 values
}

// ---------- quantize w + layout to wt[s][co][ci] bf16 ----------
__global__ void k_quant_wt(const float* __restrict__ w, unsigned short* __restrict__ wt) {
    int g = threadIdx.x;            // 1 block, 256 threads = 256 groups exactly
    int base = g * GSZ;
    float v[GSZ];
    const float4* p = reinterpret_cast<const float4*>(w + base);
    #pragma unroll
    for (int i = 0; i < 9; ++i) {
        float4 t = p[i];
        v[4*i+0] = t.x; v[4*i+1] = t.y; v[4*i+2] = t.z; v[4*i+3] = t.w;
    }
    float m = 0.0f;
    #pragma unroll
    for (int i = 0; i < GSZ; ++i) m = fmaxf(m, fabsf(v[i]));
    if (m > 0.0f) {
        float s = scale_from_max(m), inv = inv_from_scale(s);
        #pragma unroll
        for (int i = 0; i < GSZ; ++i) v[i] = rintf(v[i] * inv) * s;
    }
    #pragma unroll
    for (int i = 0; i < GSZ; ++i) {
        int f = base + i;
        int co = f / 288, rem = f - co * 288;
        int ci = rem / 9, s = rem - ci * 9;
        wt[s * 1024 + co * 32 + ci] = f2bf(v[i]);
    }
}

// ---------- fused x: BFP-quantize (flat-36 groups) + NCHW->NHWC, one pass ----------
// Coalesced cover loads held in REGISTERS (16 f32x4/thread), per-float4 partial
// max -> private LDS slot (no atomics: groups are float4-aligned since 36 = 9*4
// and all group starts are 4-aligned), 448 group-tasks reduce 9 partials ->
// scale, then quantize from regs. One global pass, no atomics.
#define TSTR 452   // bf16 tile row stride (bank-spread, keeps uint2 writes 8B-aligned)
__global__ __launch_bounds__(256, 4) void k_quant_x_fused(const float* __restrict__ x,
                                                          unsigned short* __restrict__ xt) {
    __shared__ __align__(16) unsigned char raw[32 * TSTR * 2];   // 28,928 B
    unsigned short* tile = reinterpret_cast<unsigned short*>(raw);   // phase C/D
    float* pmax = reinterpret_cast<float*>(raw);                     // phase A/B (16,384 B)
    __shared__ float scl[32 * 14];                                   // 1,792 B

    int t = threadIdx.x;
    int b = blockIdx.y, hp = blockIdx.x;
    int F0 = (b * 32) * HWp + hp * 448;

    int c4  = t & 127;          // float4 index within the 128-float4 cover
    int ciB = t >> 7;           // 0 or 1; thread's ci set = {ciB + 2j}

    // Phase A: coalesced group-aligned cover loads into regs; partial max -> LDS
    f32x4 v[16];
    #pragma unroll
    for (int j = 0; j < 16; ++j) {
        int ci = ciB + 2 * j;
        int F = F0 + ci * HWp;
        int r = F - 36 * (int)div36((unsigned)F);            // F % 36 (multiple of 4)
        int f4 = (int)(((unsigned)(F - r)) >> 2) + c4;       // cover float4 index
        f32x4 tv = {0.f, 0.f, 0.f, 0.f};
        if ((unsigned)f4 < (unsigned)NX4)
            tv = reinterpret_cast<const f32x4*>(x)[f4];
        v[j] = tv;
        pmax[ci * 128 + c4] = fmaxf(fmaxf(fabsf(tv[0]), fabsf(tv[1])),
                                    fmaxf(fabsf(tv[2]), fabsf(tv[3])));
    }
    __syncthreads();

    // Phase B: group max = max of 9 consecutive partials -> scale (0 = all-zero group)
    #pragma unroll
    for (int it = 0; it < 2; ++it) {
        int task = t + 256 * it;
        if (task < 448) {
            int ci = (task * 2341) >> 15;                    // task / 14, exact
            int gi = task - ci * 14;
            const float* pp = &pmax[ci * 128 + 9 * gi];
            float m = pp[0];
            #pragma unroll
            for (int i = 1; i < 9; ++i) m = fmaxf(m, pp[i]);
            scl[task] = (m > 0.f) ? scale_from_max(m) : 0.f;
        }
    }
    __syncthreads();

    // Phase C: quantize held regs, pack bf16 into tile (overwrites pmax region)
    int gi4 = (c4 * 57) >> 9;                                // c4 / 9, exact for c4 < 128
    #pragma unroll
    for (int j = 0; j < 16; ++j) {
        int ci = ciB + 2 * j;
        int F = F0 + ci * HWp;
        int r = F - 36 * (int)div36((unsigned)F);
        int rel = 4 * c4 - r;                                // tile-relative elem offset
        if ((unsigned)rel < 448u) {
            float s = scl[ci * 14 + gi4];
            f32x4 q = v[j];
            if (s > 0.f) {
                float inv = inv_from_scale(s);
                #pragma unroll
                for (int k = 0; k < 4; ++k) q[k] = rintf(q[k] * inv) * s;
            } else {
                q = f32x4{0.f, 0.f, 0.f, 0.f};
            }
            uint2 o;
            o.x = (unsigned)f2bf(q[0]) | ((unsigned)f2bf(q[1]) << 16);
            o.y = (unsigned)f2bf(q[2]) | ((unsigned)f2bf(q[3]) << 16);
            *reinterpret_cast<uint2*>(&tile[ci * TSTR + rel]) = o;
        }
    }
    __syncthreads();

    // Phase D: gather 8 ci per pixel, coalesced 16B NHWC stores
    unsigned short* ob = xt + ((size_t)b * HWp + hp * 448) * 32;
    for (int j = 0; j < 7; ++j) {
        int qd = t + 256 * j;                      // 1792 16B-chunks
        int px = qd >> 2;
        int c0 = (qd & 3) * 8;
        unsigned uu[4];
        #pragma unroll
        for (int p = 0; p < 4; ++p) {
            unsigned short lo = tile[(c0 + 2 * p) * TSTR + px];
            unsigned short hi = tile[(c0 + 2 * p + 1) * TSTR + px];
            uu[p] = (unsigned)lo | ((unsigned)hi << 16);
        }
        *reinterpret_cast<uint4*>(ob + (size_t)px * 32 + c0) =
            make_uint4(uu[0], uu[1], uu[2], uu[3]);
    }
}

// ---------- MFMA conv: 3x3 SAME as 9 shifted K=32 GEMMs, coalesced epilogue ----------
// mfma(A=w_frag[m=co], B=x_frag[n=px]) -> D row=co, col=px. Writes f32 result to
// the workspace buffer cbuf (NOT the final out) so the out-quant pass can run as
// two decoupled pure streams (no in-place RMW).
#define PXS 40
__global__ __launch_bounds__(256, 2) void k_conv_mfma(const unsigned short* __restrict__ xt,
                                                      const unsigned short* __restrict__ wt,
                                                      const float* __restrict__ bias,
                                                      float* __restrict__ cbuf) {
    __shared__ __align__(16) unsigned short xs[18 * 34 * PXS];  // 48,960 B

    int tid  = threadIdx.x;
    int lane = tid & 63;
    int wid  = tid >> 6;
    int b  = blockIdx.z;
    int h0 = blockIdx.y * 16;
    int w0 = blockIdx.x * 32;

    // stage 18x34 halo (all 32 ci) from NHWC
    const unsigned short* xb = xt + (size_t)b * HWp * 32;
    #pragma unroll
    for (int k = 0; k < 10; ++k) {
        int q = tid + k * 256;
        if (q < 2448) {                       // 18*34*4 16B-chunks
            int r = q / 136;
            int rem = q - r * 136;
            int p = rem >> 2, ch = rem & 3;
            int gh = h0 + r - 1, gw = w0 + p - 1;
            uint4 val = make_uint4(0u, 0u, 0u, 0u);
            if ((unsigned)gh < 224u && (unsigned)gw < 224u)
                val = *reinterpret_cast<const uint4*>(xb + ((size_t)(gh * 224 + gw)) * 32 + ch * 8);
            *reinterpret_cast<uint4*>(&xs[(r * 34 + p) * PXS + ch * 8]) = val;
        }
    }

    // weight fragments (A-operand: m=lane&15=co, k=(lane>>4)*8+j=ci)
    bf16x8 Wf[9][2];
    #pragma unroll
    for (int s = 0; s < 9; ++s)
        #pragma unroll
        for (int hf = 0; hf < 2; ++hf)
            Wf[s][hf] = *reinterpret_cast<const bf16x8*>(
                wt + s * 1024 + (hf * 16 + (lane & 15)) * 32 + (lane >> 4) * 8);

    // acc init = bias; D row = co = (lane>>4)*4 + reg (+16*hf)
    int m4 = (lane >> 4) << 2;
    f32x4 acc[8][2];
    {
        f32x4 b0, b1;
        #pragma unroll
        for (int r = 0; r < 4; ++r) {
            b0[r] = bias[m4 + r];
            b1[r] = bias[16 + m4 + r];
        }
        #pragma unroll
        for (int g = 0; g < 8; ++g) { acc[g][0] = b0; acc[g][1] = b1; }
    }

    __syncthreads();

    int row4 = wid << 2;
    int kchunk = (lane >> 4) << 3;
    #pragma unroll
    for (int s = 0; s < 9; ++s) {
        int kh = s / 3, kw = s - kh * 3;
        #pragma unroll
        for (int g = 0; g < 8; ++g) {
            int row = row4 + (g >> 1);
            int col = ((g & 1) << 4) + (lane & 15);
            bf16x8 X = *reinterpret_cast<const bf16x8*>(
                &xs[((row + kh) * 34 + col + kw) * PXS + kchunk]);
            acc[g][0] = __builtin_amdgcn_mfma_f32_16x16x32_bf16(Wf[s][0], X, acc[g][0], 0, 0, 0);
            acc[g][1] = __builtin_amdgcn_mfma_f32_16x16x32_bf16(Wf[s][1], X, acc[g][1], 0, 0, 0);
        }
    }

    // epilogue: col = lane&15 = px, row = m4 + reg = co -> line-coalesced stores
    int pxl = lane & 15;
    #pragma unroll
    for (int g = 0; g < 8; ++g) {
        int h = h0 + row4 + (g >> 1);
        int wl = w0 + ((g & 1) << 4) + pxl;
        size_t base = (size_t)(b * 32) * HWp + h * 224 + wl;
        #pragma unroll
        for (int hf = 0; hf < 2; ++hf)
            #pragma unroll
            for (int r = 0; r < 4; ++r)
                cbuf[base + (size_t)((hf << 4) + m4 + r) * HWp] = acc[g][hf][r];
    }
}

// ---------- out-quant, OUT-OF-PLACE: pure read stream (cbuf) -> pure write (out) ----
// 9 lanes own one 36-elem group (9 float4). Lanes 0..62 of a wave cover 7 whole
// groups; the 63 float4 loads are contiguous -> fully coalesced. Group max via
// 4 rotate-max shuffle steps (rot 1,2,4,8 mod 9). Distinct restrict pointers:
// no alias ordering between stores and subsequent loads.
#define QOG 112   // groups per wave (7 groups/iter * 16 iters)
__global__ __launch_bounds__(256) void k_quant_out(const float* __restrict__ src,
                                                   float* __restrict__ dst) {
    int t = threadIdx.x, lane = t & 63, wid = t >> 6;
    int s9 = (lane * 57) >> 9;          // lane / 9, exact for lane < 64
    int p9 = lane - s9 * 9;
    bool active = lane < 63;

    // per-thread-constant shuffle source lanes: rotate within the 9-lane set
    int src_ln[4];
    #pragma unroll
    for (int k = 0; k < 4; ++k) {
        int rot = 1 << k;               // 1, 2, 4, 8
        int pp = p9 + rot; if (pp >= 9) pp -= 9;
        src_ln[k] = active ? (s9 * 9 + pp) : 63;
    }

    int wave_g = (blockIdx.x * 4 + wid) * QOG;     // first group of this wave
    #pragma unroll 4
    for (int i = 0; i < 16; ++i) {
        int f4 = (wave_g + 7 * i) * 9 + lane;      // contiguous across lanes 0..62
        bool ld = active && (unsigned)f4 < (unsigned)NX4;
        f32x4 v = {0.f, 0.f, 0.f, 0.f};
        if (ld) v = reinterpret_cast<const f32x4*>(src)[f4];
        float m = fmaxf(fmaxf(fabsf(v[0]), fabsf(v[1])),
                        fmaxf(fabsf(v[2]), fabsf(v[3])));
        #pragma unroll
        for (int k = 0; k < 4; ++k)
            m = fmaxf(m, __shfl(m, src_ln[k]));
        if (m > 0.f) {
            float s = scale_from_max(m), inv = inv_from_scale(s);
            #pragma unroll
            for (int k = 0; k < 4; ++k) v[k] = rintf(v[k] * inv) * s;
        }
        if (ld) reinterpret_cast<f32x4*>(dst)[f4] = v;
    }
}

extern "C" void kernel_launch(void* const* d_in, const int* in_sizes, int n_in,
                              void* d_out, int out_size, void* d_ws, size_t ws_size,
                              hipStream_t stream) {
    (void)in_sizes; (void)n_in; (void)out_size; (void)ws_size;
    const float* x    = (const float*)d_in[0];
    const float* w    = (const float*)d_in[1];
    const float* bias = (const float*)d_in[2];
    float* out        = (float*)d_out;

    unsigned short* xt = (unsigned short*)d_ws;   // NX bf16 NHWC (51.4 MB)
    unsigned short* wt = xt + NX;                 // 9,216 bf16
    float* cbuf = (float*)(wt + NW);              // NX f32 conv result (102.8 MB), 16B-aligned

    k_quant_wt<<<1, 256, 0, stream>>>(w, wt);
    k_quant_x_fused<<<dim3(112, 16), 256, 0, stream>>>(x, xt);
    k_conv_mfma<<<dim3(7, 14, 16), 256, 0, stream>>>(xt, wt, bias, cbuf);
    // 1593 blocks: ceil(713615 / (4 waves * 112 groups))
    k_quant_out<<<1593, 256, 0, stream>>>(cbuf, out);
}

// Round 6
// 249.147 us; speedup vs baseline: 1.0542x; 1.0542x over previous
//
#include <hip/hip_runtime.h>
#include <hip/hip_bf16.h>

#define GSZ 36
static const int NX  = 16 * 32 * 224 * 224;     // 25,690,112
static const int NX4 = NX / 4;                  // 6,422,528 (NX % 4 == 0)
static const int NW  = 32 * 32 * 3 * 3;         // 9,216
static const int GXN = (NX + GSZ - 1) / GSZ;    // 713,615
static const int HWp = 224 * 224;               // 50,176 = 448 * 112

typedef short bf16x8 __attribute__((ext_vector_type(8)));
typedef float f32x4  __attribute__((ext_vector_type(4)));

// floor(n/36), exact for n < 2^31
__device__ __forceinline__ unsigned div36(unsigned n) {
    return (unsigned)(((unsigned long long)n * 954437177ull) >> 35);
}
// scale = 2^(floor(log2 m) - 7) via exponent field (m normal > 0)
__device__ __forceinline__ float scale_from_max(float m) {
    int e = (int)((__float_as_uint(m) >> 23) & 0xffu) - 127;
    return __uint_as_float((unsigned)(e + 120) << 23);
}
// 1/scale for power-of-two scale: bits = 0x7F000000 - scale_bits
__device__ __forceinline__ float inv_from_scale(float s) {
    return __uint_as_float(0x7F000000u - __float_as_uint(s));
}
__device__ __forceinline__ unsigned short f2bf(float f) {
    return (unsigned short)(__float_as_uint(f) >> 16);  // exact for BFP-8 values
}

// ---------- quantize w + layout to wt[s][co][ci] bf16 ----------
__global__ void k_quant_wt(const float* __restrict__ w, unsigned short* __restrict__ wt) {
    int g = threadIdx.x;            // 1 block, 256 threads = 256 groups exactly
    int base = g * GSZ;
    float v[GSZ];
    const float4* p = reinterpret_cast<const float4*>(w + base);
    #pragma unroll
    for (int i = 0; i < 9; ++i) {
        float4 t = p[i];
        v[4*i+0] = t.x; v[4*i+1] = t.y; v[4*i+2] = t.z; v[4*i+3] = t.w;
    }
    float m = 0.0f;
    #pragma unroll
    for (int i = 0; i < GSZ; ++i) m = fmaxf(m, fabsf(v[i]));
    if (m > 0.0f) {
        float s = scale_from_max(m), inv = inv_from_scale(s);
        #pragma unroll
        for (int i = 0; i < GSZ; ++i) v[i] = rintf(v[i] * inv) * s;
    }
    #pragma unroll
    for (int i = 0; i < GSZ; ++i) {
        int f = base + i;
        int co = f / 288, rem = f - co * 288;
        int ci = rem / 9, s = rem - ci * 9;
        wt[s * 1024 + co * 32 + ci] = f2bf(v[i]);
    }
}

// ---------- fused x: BFP-quantize (flat-36 groups) + NCHW->NHWC, one pass ----------
#define TSTR 452   // bf16 tile row stride
__global__ __launch_bounds__(256, 4) void k_quant_x_fused(const float* __restrict__ x,
                                                          unsigned short* __restrict__ xt) {
    __shared__ __align__(16) unsigned char raw[32 * TSTR * 2];   // 28,928 B
    unsigned short* tile = reinterpret_cast<unsigned short*>(raw);   // phase C/D
    float* pmax = reinterpret_cast<float*>(raw);                     // phase A/B (16,384 B)
    __shared__ float scl[32 * 14];                                   // 1,792 B

    int t = threadIdx.x;
    int b = blockIdx.y, hp = blockIdx.x;
    int F0 = (b * 32) * HWp + hp * 448;

    int c4  = t & 127;          // float4 index within the 128-float4 cover
    int ciB = t >> 7;           // 0 or 1; thread's ci set = {ciB + 2j}

    // Phase A: coalesced group-aligned cover loads into regs; partial max -> LDS
    f32x4 v[16];
    #pragma unroll
    for (int j = 0; j < 16; ++j) {
        int ci = ciB + 2 * j;
        int F = F0 + ci * HWp;
        int r = F - 36 * (int)div36((unsigned)F);            // F % 36 (multiple of 4)
        int f4 = (int)(((unsigned)(F - r)) >> 2) + c4;       // cover float4 index
        f32x4 tv = {0.f, 0.f, 0.f, 0.f};
        if ((unsigned)f4 < (unsigned)NX4)
            tv = reinterpret_cast<const f32x4*>(x)[f4];
        v[j] = tv;
        pmax[ci * 128 + c4] = fmaxf(fmaxf(fabsf(tv[0]), fabsf(tv[1])),
                                    fmaxf(fabsf(tv[2]), fabsf(tv[3])));
    }
    __syncthreads();

    // Phase B: group max = max of 9 consecutive partials -> scale (0 = all-zero group)
    #pragma unroll
    for (int it = 0; it < 2; ++it) {
        int task = t + 256 * it;
        if (task < 448) {
            int ci = (task * 2341) >> 15;                    // task / 14, exact
            int gi = task - ci * 14;
            const float* pp = &pmax[ci * 128 + 9 * gi];
            float m = pp[0];
            #pragma unroll
            for (int i = 1; i < 9; ++i) m = fmaxf(m, pp[i]);
            scl[task] = (m > 0.f) ? scale_from_max(m) : 0.f;
        }
    }
    __syncthreads();

    // Phase C: quantize held regs, pack bf16 into tile (overwrites pmax region)
    int gi4 = (c4 * 57) >> 9;                                // c4 / 9, exact for c4 < 128
    #pragma unroll
    for (int j = 0; j < 16; ++j) {
        int ci = ciB + 2 * j;
        int F = F0 + ci * HWp;
        int r = F - 36 * (int)div36((unsigned)F);
        int rel = 4 * c4 - r;                                // tile-relative elem offset
        if ((unsigned)rel < 448u) {
            float s = scl[ci * 14 + gi4];
            f32x4 q = v[j];
            if (s > 0.f) {
                float inv = inv_from_scale(s);
                #pragma unroll
                for (int k = 0; k < 4; ++k) q[k] = rintf(q[k] * inv) * s;
            } else {
                q = f32x4{0.f, 0.f, 0.f, 0.f};
            }
            uint2 o;
            o.x = (unsigned)f2bf(q[0]) | ((unsigned)f2bf(q[1]) << 16);
            o.y = (unsigned)f2bf(q[2]) | ((unsigned)f2bf(q[3]) << 16);
            *reinterpret_cast<uint2*>(&tile[ci * TSTR + rel]) = o;
        }
    }
    __syncthreads();

    // Phase D: gather 8 ci per pixel, coalesced 16B NHWC stores
    unsigned short* ob = xt + ((size_t)b * HWp + hp * 448) * 32;
    for (int j = 0; j < 7; ++j) {
        int qd = t + 256 * j;                      // 1792 16B-chunks
        int px = qd >> 2;
        int c0 = (qd & 3) * 8;
        unsigned uu[4];
        #pragma unroll
        for (int p = 0; p < 4; ++p) {
            unsigned short lo = tile[(c0 + 2 * p) * TSTR + px];
            unsigned short hi = tile[(c0 + 2 * p + 1) * TSTR + px];
            uu[p] = (unsigned)lo | ((unsigned)hi << 16);
        }
        *reinterpret_cast<uint4*>(ob + (size_t)px * 32 + c0) =
            make_uint4(uu[0], uu[1], uu[2], uu[3]);
    }
}

// ---------- fused MFMA conv + out-quant epilogue ----------
// Block = 2 full rows x 224 px x 32 co for one b. Per co the output is one flat
// 448-ALIGNED segment (HWp = 448*112), so quant groups fully inside the segment
// are quantized here (through an LDS [co][452] f32 tile reusing the x-stage LDS);
// groups straddling 448-boundaries (1/14 of groups) are written RAW and fixed by
// k_fixup afterwards.
#define PXS 40
#define COS 452
__global__ __launch_bounds__(256, 2) void k_conv_q(const unsigned short* __restrict__ xt,
                                                   const unsigned short* __restrict__ wt,
                                                   const float* __restrict__ bias,
                                                   float* __restrict__ out) {
    __shared__ __align__(16) unsigned char lraw[4 * 226 * PXS * 2];  // 72,320 B union
    unsigned short* xs = reinterpret_cast<unsigned short*>(lraw);    // [4][226][PXS] bf16
    float* ot = reinterpret_cast<float*>(lraw);                      // [32][COS] f32 (57,856 B)
    __shared__ float scl[32 * 12];
    __shared__ int rel0s[32], bnds[32];

    int tid  = threadIdx.x;
    int lane = tid & 63;
    int wid  = tid >> 6;
    int hpair = blockIdx.x;        // 0..111
    int b     = blockIdx.y;        // 0..15
    int h0 = hpair * 2;

    // per-co group alignment within the 448-segment
    if (tid < 32) {
        int T = (b * 32 + tid) * HWp + hpair * 448;          // 448-aligned, mult of 4
        int r36 = T - 36 * (int)div36((unsigned)T);
        int rel0 = r36 ? 36 - r36 : 0;                       // first full-group offset
        rel0s[tid] = rel0;
        bnds[tid] = rel0 + 36 * (int)div36((unsigned)(448 - rel0));  // end of full zone
    }

    // stage 4 rows (h0-1..h0+2) x 226 px x 32 ci from NHWC
    const unsigned short* xb = xt + (size_t)b * HWp * 32;
    for (int k = 0; k < 15; ++k) {
        int q = tid + k * 256;
        if (q < 3616) {                        // 4*226*4 16B-chunks
            int r = ((q >> 3) * 145) >> 14;    // (q/8)/113, exact for q<3616
            int rem = q - r * 904;
            int p = rem >> 2, ch = rem & 3;
            int gh = h0 - 1 + r, gw = p - 1;
            uint4 val = make_uint4(0u, 0u, 0u, 0u);
            if ((unsigned)gh < 224u && (unsigned)gw < 224u)
                val = *reinterpret_cast<const uint4*>(xb + ((size_t)(gh * 224 + gw)) * 32 + ch * 8);
            *reinterpret_cast<uint4*>(&xs[(r * 226 + p) * PXS + ch * 8]) = val;
        }
    }

    // weight fragments (A-operand: m=lane&15=co, k=(lane>>4)*8+j=ci)
    bf16x8 Wf[9][2];
    #pragma unroll
    for (int s = 0; s < 9; ++s)
        #pragma unroll
        for (int hf = 0; hf < 2; ++hf)
            Wf[s][hf] = *reinterpret_cast<const bf16x8*>(
                wt + s * 1024 + (hf * 16 + (lane & 15)) * 32 + (lane >> 4) * 8);

    // acc init = bias
    int m4 = (lane >> 4) << 2;
    f32x4 acc[7][2];
    {
        f32x4 b0, b1;
        #pragma unroll
        for (int r = 0; r < 4; ++r) {
            b0[r] = bias[m4 + r];
            b1[r] = bias[16 + m4 + r];
        }
        #pragma unroll
        for (int i = 0; i < 7; ++i) { acc[i][0] = b0; acc[i][1] = b1; }
    }

    __syncthreads();

    // MFMA: wave owns 7 of 28 px fragments (frag f: row=f/14, col=(f%14)*16)
    int l15 = lane & 15;
    int kchunk = (lane >> 4) << 3;
    #pragma unroll
    for (int s = 0; s < 9; ++s) {
        int kh = s / 3, kw = s - kh * 3;
        #pragma unroll
        for (int i = 0; i < 7; ++i) {
            int f = wid * 7 + i;
            int row = (f >= 14) ? 1 : 0;
            int colf = (f - 14 * row) << 4;
            bf16x8 X = *reinterpret_cast<const bf16x8*>(
                &xs[((row + kh) * 226 + colf + l15 + kw) * PXS + kchunk]);
            acc[i][0] = __builtin_amdgcn_mfma_f32_16x16x32_bf16(Wf[s][0], X, acc[i][0], 0, 0, 0);
            acc[i][1] = __builtin_amdgcn_mfma_f32_16x16x32_bf16(Wf[s][1], X, acc[i][1], 0, 0, 0);
        }
    }
    __syncthreads();   // all xs reads done; lraw becomes ot

    // acc -> ot[co][px448]   (2-way bank aliasing only)
    #pragma unroll
    for (int i = 0; i < 7; ++i) {
        int f = wid * 7 + i;
        int row = (f >= 14) ? 1 : 0;
        int px = row * 224 + ((f - 14 * row) << 4) + l15;
        #pragma unroll
        for (int hf = 0; hf < 2; ++hf)
            #pragma unroll
            for (int r = 0; r < 4; ++r)
                ot[(hf * 16 + m4 + r) * COS + px] = acc[i][hf][r];
    }
    __syncthreads();

    // scales for full groups: 32 co x up to 12 groups
    #pragma unroll
    for (int it = 0; it < 2; ++it) {
        int task = tid + it * 256;
        if (task < 384) {
            int co = ((task >> 2) * 683) >> 11;          // task/12 = (task>>2)/3
            int k = task - co * 12;
            int base = rel0s[co] + 36 * k;
            if (base < bnds[co]) {
                const float* pp = &ot[co * COS + base];
                float m = 0.f;
                #pragma unroll
                for (int i = 0; i < 9; ++i) {
                    f32x4 vv = *reinterpret_cast<const f32x4*>(pp + 4 * i);
                    m = fmaxf(m, fmaxf(fmaxf(fabsf(vv[0]), fabsf(vv[1])),
                                       fmaxf(fabsf(vv[2]), fabsf(vv[3]))));
                }
                scl[co * 12 + k] = (m > 0.f) ? scale_from_max(m) : 0.f;
            }
        }
    }
    __syncthreads();

    // quantize + store: 3584 f32x4 chunks; each chunk lies in ONE group
    // (group boundaries and chunk starts are both multiples of 4)
    float* ob = out + (size_t)(b * 32) * HWp + h0 * 224;
    #pragma unroll
    for (int j = 0; j < 14; ++j) {
        int idx = tid + j * 256;
        int co = ((idx >> 4) * 2341) >> 14;              // idx/112 = (idx>>4)/7
        int c4 = idx - co * 112;
        int px0 = c4 * 4;
        f32x4 v = *reinterpret_cast<const f32x4*>(&ot[co * COS + px0]);
        int rz = px0 - rel0s[co];
        if ((unsigned)rz < (unsigned)(bnds[co] - rel0s[co])) {   // full-group zone
            int k = (int)div36((unsigned)rz);
            float s = scl[co * 12 + k];
            if (s > 0.f) {
                float inv = inv_from_scale(s);
                #pragma unroll
                for (int e = 0; e < 4; ++e) v[e] = rintf(v[e] * inv) * s;
            } else {
                v = f32x4{0.f, 0.f, 0.f, 0.f};
            }
        }
        // else: straddle zone -> raw value, k_fixup quantizes later
        *reinterpret_cast<f32x4*>(ob + (size_t)co * HWp + px0) = v;
    }
}

// ---------- fixup: quantize the 448-boundary-straddling groups in place ----------
// Straddle groups: g mod 112 in {12,24,37,49,62,74,87,99} (8 per 112).
__global__ __launch_bounds__(256) void k_fixup(float* __restrict__ buf) {
    int i = blockIdx.x * 256 + threadIdx.x;
    if (i >= 50976) return;
    const unsigned long long SP =
        12ull | (24ull << 7) | (37ull << 14) | (49ull << 21) |
        (62ull << 28) | (74ull << 35) | (87ull << 42) | (99ull << 49);
    int g = (i >> 3) * 112 + (int)((SP >> (7 * (i & 7))) & 127ull);
    if (g >= GXN) return;
    int f4 = 9 * g;                       // 36g/4
    f32x4 v[9];
    float m = 0.f;
    #pragma unroll
    for (int k = 0; k < 9; ++k) {
        f32x4 tv = {0.f, 0.f, 0.f, 0.f};
        if ((unsigned)(f4 + k) < (unsigned)NX4)
            tv = reinterpret_cast<const f32x4*>(buf)[f4 + k];
        v[k] = tv;
        m = fmaxf(m, fmaxf(fmaxf(fabsf(tv[0]), fabsf(tv[1])),
                           fmaxf(fabsf(tv[2]), fabsf(tv[3]))));
    }
    if (m > 0.f) {
        float s = scale_from_max(m), inv = inv_from_scale(s);
        #pragma unroll
        for (int k = 0; k < 9; ++k) {
            #pragma unroll
            for (int e = 0; e < 4; ++e) v[k][e] = rintf(v[k][e] * inv) * s;
            if ((unsigned)(f4 + k) < (unsigned)NX4)
                reinterpret_cast<f32x4*>(buf)[f4 + k] = v[k];
        }
    }
}

extern "C" void kernel_launch(void* const* d_in, const int* in_sizes, int n_in,
                              void* d_out, int out_size, void* d_ws, size_t ws_size,
                              hipStream_t stream) {
    (void)in_sizes; (void)n_in; (void)out_size; (void)ws_size;
    const float* x    = (const float*)d_in[0];
    const float* w    = (const float*)d_in[1];
    const float* bias = (const float*)d_in[2];
    float* out        = (float*)d_out;

    unsigned short* xt = (unsigned short*)d_ws;   // NX bf16 NHWC (51.4 MB)
    unsigned short* wt = xt + NX;                 // 9,216 bf16

    k_quant_wt<<<1, 256, 0, stream>>>(w, wt);
    k_quant_x_fused<<<dim3(112, 16), 256, 0, stream>>>(x, xt);
    k_conv_q<<<dim3(112, 16), 256, 0, stream>>>(xt, wt, bias, out);
    k_fixup<<<200, 256, 0, stream>>>(out);        // 50,976 straddle-group slots
}

// Round 7
// 247.673 us; speedup vs baseline: 1.0604x; 1.0060x over previous
//
#include <hip/hip_runtime.h>
#include <hip/hip_bf16.h>

#define GSZ 36
static const int NX  = 16 * 32 * 224 * 224;     // 25,690,112
static const int NX4 = NX / 4;                  // 6,422,528 (NX % 4 == 0)
static const int NW  = 32 * 32 * 3 * 3;         // 9,216
static const int GXN = (NX + GSZ - 1) / GSZ;    // 713,615
static const int HWp = 224 * 224;               // 50,176 = 448 * 112

typedef short bf16x8 __attribute__((ext_vector_type(8)));
typedef float f32x4  __attribute__((ext_vector_type(4)));

// floor(n/36), exact for n < 2^31
__device__ __forceinline__ unsigned div36(unsigned n) {
    return (unsigned)(((unsigned long long)n * 954437177ull) >> 35);
}
// scale = 2^(floor(log2 m) - 7) via exponent field (m normal > 0)
__device__ __forceinline__ float scale_from_max(float m) {
    int e = (int)((__float_as_uint(m) >> 23) & 0xffu) - 127;
    return __uint_as_float((unsigned)(e + 120) << 23);
}
// 1/scale for power-of-two scale: bits = 0x7F000000 - scale_bits
__device__ __forceinline__ float inv_from_scale(float s) {
    return __uint_as_float(0x7F000000u - __float_as_uint(s));
}
__device__ __forceinline__ unsigned short f2bf(float f) {
    return (unsigned short)(__float_as_uint(f) >> 16);  // exact for BFP-8 values
}

// ---------- quantize w + layout to wt[s][co][ci] bf16 ----------
__global__ void k_quant_wt(const float* __restrict__ w, unsigned short* __restrict__ wt) {
    int g = threadIdx.x;            // 1 block, 256 threads = 256 groups exactly
    int base = g * GSZ;
    float v[GSZ];
    const float4* p = reinterpret_cast<const float4*>(w + base);
    #pragma unroll
    for (int i = 0; i < 9; ++i) {
        float4 t = p[i];
        v[4*i+0] = t.x; v[4*i+1] = t.y; v[4*i+2] = t.z; v[4*i+3] = t.w;
    }
    float m = 0.0f;
    #pragma unroll
    for (int i = 0; i < GSZ; ++i) m = fmaxf(m, fabsf(v[i]));
    if (m > 0.0f) {
        float s = scale_from_max(m), inv = inv_from_scale(s);
        #pragma unroll
        for (int i = 0; i < GSZ; ++i) v[i] = rintf(v[i] * inv) * s;
    }
    #pragma unroll
    for (int i = 0; i < GSZ; ++i) {
        int f = base + i;
        int co = f / 288, rem = f - co * 288;
        int ci = rem / 9, s = rem - ci * 9;
        wt[s * 1024 + co * 32 + ci] = f2bf(v[i]);
    }
}

// ---------- fused x: BFP-quantize (flat-36 groups) + NCHW->NHWC, one pass ----------
// Round 7: TWO ci-HALVES of 8 f32x4 each (32 VGPR payload, was 64) to eliminate
// register spills under __launch_bounds__(256,4). pmax is its own 8KB buffer
// (16 ci x 128 chunk-maxes, reused across halves); tile filled half-by-half.
#define TSTR 452   // bf16 tile row stride
__global__ __launch_bounds__(256, 4) void k_quant_x_fused(const float* __restrict__ x,
                                                          unsigned short* __restrict__ xt) {
    __shared__ __align__(16) unsigned short tile[32 * TSTR];  // 28,928 B
    __shared__ float pmax[16 * 128];                          //  8,192 B (one ci-half)
    __shared__ float scl[32 * 14];                            //  1,792 B

    int t = threadIdx.x;
    int b = blockIdx.y, hp = blockIdx.x;
    int F0 = (b * 32) * HWp + hp * 448;

    int c4  = t & 127;          // float4 index within the 128-float4 cover
    int ciB = t >> 7;           // 0 or 1; thread's ci_local set = {ciB + 2j}
    int gi4 = (c4 * 57) >> 9;   // c4 / 9, exact for c4 < 128

    #pragma unroll
    for (int h = 0; h < 2; ++h) {
        f32x4 v[8];
        // Phase A: coalesced group-aligned cover loads into regs; chunk max -> pmax
        #pragma unroll
        for (int j = 0; j < 8; ++j) {
            int cl = ciB + 2 * j;                            // ci_local 0..15
            int ci = h * 16 + cl;
            int F = F0 + ci * HWp;
            int r = F - 36 * (int)div36((unsigned)F);        // F % 36 (multiple of 4)
            int f4 = (int)(((unsigned)(F - r)) >> 2) + c4;   // cover float4 index
            f32x4 tv = {0.f, 0.f, 0.f, 0.f};
            if ((unsigned)f4 < (unsigned)NX4)
                tv = reinterpret_cast<const f32x4*>(x)[f4];
            v[j] = tv;
            pmax[cl * 128 + c4] = fmaxf(fmaxf(fabsf(tv[0]), fabsf(tv[1])),
                                        fmaxf(fabsf(tv[2]), fabsf(tv[3])));
        }
        __syncthreads();

        // Phase B: group max = max of 9 consecutive chunk-maxes -> scale
        if (t < 224) {                                       // 16 ci x 14 groups
            int cl = (t * 2341) >> 15;                       // t / 14, exact
            int gi = t - cl * 14;
            const float* pp = &pmax[cl * 128 + 9 * gi];
            float m = pp[0];
            #pragma unroll
            for (int i = 1; i < 9; ++i) m = fmaxf(m, pp[i]);
            scl[(h * 16 + cl) * 14 + gi] = (m > 0.f) ? scale_from_max(m) : 0.f;
        }
        __syncthreads();

        // Phase C: quantize held regs, pack bf16 into tile
        #pragma unroll
        for (int j = 0; j < 8; ++j) {
            int ci = h * 16 + ciB + 2 * j;
            int F = F0 + ci * HWp;
            int r = F - 36 * (int)div36((unsigned)F);
            int rel = 4 * c4 - r;                            // tile-relative elem offset
            if ((unsigned)rel < 448u) {
                float s = scl[ci * 14 + gi4];
                f32x4 q = v[j];
                if (s > 0.f) {
                    float inv = inv_from_scale(s);
                    #pragma unroll
                    for (int k = 0; k < 4; ++k) q[k] = rintf(q[k] * inv) * s;
                } else {
                    q = f32x4{0.f, 0.f, 0.f, 0.f};
                }
                uint2 o;
                o.x = (unsigned)f2bf(q[0]) | ((unsigned)f2bf(q[1]) << 16);
                o.y = (unsigned)f2bf(q[2]) | ((unsigned)f2bf(q[3]) << 16);
                *reinterpret_cast<uint2*>(&tile[ci * TSTR + rel]) = o;
            }
        }
        __syncthreads();   // h=0: protect pmax reuse; h=1: tile ready for phase D
    }

    // Phase D: gather 8 ci per pixel, coalesced 16B NHWC stores
    unsigned short* ob = xt + ((size_t)b * HWp + hp * 448) * 32;
    for (int j = 0; j < 7; ++j) {
        int qd = t + 256 * j;                      // 1792 16B-chunks
        int px = qd >> 2;
        int c0 = (qd & 3) * 8;
        unsigned uu[4];
        #pragma unroll
        for (int p = 0; p < 4; ++p) {
            unsigned short lo = tile[(c0 + 2 * p) * TSTR + px];
            unsigned short hi = tile[(c0 + 2 * p + 1) * TSTR + px];
            uu[p] = (unsigned)lo | ((unsigned)hi << 16);
        }
        *reinterpret_cast<uint4*>(ob + (size_t)px * 32 + c0) =
            make_uint4(uu[0], uu[1], uu[2], uu[3]);
    }
}

// ---------- fused MFMA conv + out-quant epilogue ----------
// Block = 2 full rows x 224 px x 32 co for one b. Per co the output is one flat
// 448-ALIGNED segment (HWp = 448*112), so quant groups fully inside the segment
// are quantized here (through an LDS [co][452] f32 tile reusing the x-stage LDS);
// groups straddling 448-boundaries (1/14 of groups) are written RAW and fixed by
// k_fixup afterwards.
#define PXS 40
#define COS 452
__global__ __launch_bounds__(256, 2) void k_conv_q(const unsigned short* __restrict__ xt,
                                                   const unsigned short* __restrict__ wt,
                                                   const float* __restrict__ bias,
                                                   float* __restrict__ out) {
    __shared__ __align__(16) unsigned char lraw[4 * 226 * PXS * 2];  // 72,320 B union
    unsigned short* xs = reinterpret_cast<unsigned short*>(lraw);    // [4][226][PXS] bf16
    float* ot = reinterpret_cast<float*>(lraw);                      // [32][COS] f32 (57,856 B)
    __shared__ float scl[32 * 12];
    __shared__ int rel0s[32], bnds[32];

    int tid  = threadIdx.x;
    int lane = tid & 63;
    int wid  = tid >> 6;
    int hpair = blockIdx.x;        // 0..111
    int b     = blockIdx.y;        // 0..15
    int h0 = hpair * 2;

    // per-co group alignment within the 448-segment
    if (tid < 32) {
        int T = (b * 32 + tid) * HWp + hpair * 448;          // 448-aligned, mult of 4
        int r36 = T - 36 * (int)div36((unsigned)T);
        int rel0 = r36 ? 36 - r36 : 0;                       // first full-group offset
        rel0s[tid] = rel0;
        bnds[tid] = rel0 + 36 * (int)div36((unsigned)(448 - rel0));  // end of full zone
    }

    // stage 4 rows (h0-1..h0+2) x 226 px x 32 ci from NHWC
    const unsigned short* xb = xt + (size_t)b * HWp * 32;
    for (int k = 0; k < 15; ++k) {
        int q = tid + k * 256;
        if (q < 3616) {                        // 4*226*4 16B-chunks
            int r = ((q >> 3) * 145) >> 14;    // (q/8)/113, exact for q<3616
            int rem = q - r * 904;
            int p = rem >> 2, ch = rem & 3;
            int gh = h0 - 1 + r, gw = p - 1;
            uint4 val = make_uint4(0u, 0u, 0u, 0u);
            if ((unsigned)gh < 224u && (unsigned)gw < 224u)
                val = *reinterpret_cast<const uint4*>(xb + ((size_t)(gh * 224 + gw)) * 32 + ch * 8);
            *reinterpret_cast<uint4*>(&xs[(r * 226 + p) * PXS + ch * 8]) = val;
        }
    }

    // weight fragments (A-operand: m=lane&15=co, k=(lane>>4)*8+j=ci)
    bf16x8 Wf[9][2];
    #pragma unroll
    for (int s = 0; s < 9; ++s)
        #pragma unroll
        for (int hf = 0; hf < 2; ++hf)
            Wf[s][hf] = *reinterpret_cast<const bf16x8*>(
                wt + s * 1024 + (hf * 16 + (lane & 15)) * 32 + (lane >> 4) * 8);

    // acc init = bias
    int m4 = (lane >> 4) << 2;
    f32x4 acc[7][2];
    {
        f32x4 b0, b1;
        #pragma unroll
        for (int r = 0; r < 4; ++r) {
            b0[r] = bias[m4 + r];
            b1[r] = bias[16 + m4 + r];
        }
        #pragma unroll
        for (int i = 0; i < 7; ++i) { acc[i][0] = b0; acc[i][1] = b1; }
    }

    __syncthreads();

    // MFMA: wave owns 7 of 28 px fragments (frag f: row=f/14, col=(f%14)*16)
    int l15 = lane & 15;
    int kchunk = (lane >> 4) << 3;
    #pragma unroll
    for (int s = 0; s < 9; ++s) {
        int kh = s / 3, kw = s - kh * 3;
        #pragma unroll
        for (int i = 0; i < 7; ++i) {
            int f = wid * 7 + i;
            int row = (f >= 14) ? 1 : 0;
            int colf = (f - 14 * row) << 4;
            bf16x8 X = *reinterpret_cast<const bf16x8*>(
                &xs[((row + kh) * 226 + colf + l15 + kw) * PXS + kchunk]);
            acc[i][0] = __builtin_amdgcn_mfma_f32_16x16x32_bf16(Wf[s][0], X, acc[i][0], 0, 0, 0);
            acc[i][1] = __builtin_amdgcn_mfma_f32_16x16x32_bf16(Wf[s][1], X, acc[i][1], 0, 0, 0);
        }
    }
    __syncthreads();   // all xs reads done; lraw becomes ot

    // acc -> ot[co][px448]   (2-way bank aliasing only)
    #pragma unroll
    for (int i = 0; i < 7; ++i) {
        int f = wid * 7 + i;
        int row = (f >= 14) ? 1 : 0;
        int px = row * 224 + ((f - 14 * row) << 4) + l15;
        #pragma unroll
        for (int hf = 0; hf < 2; ++hf)
            #pragma unroll
            for (int r = 0; r < 4; ++r)
                ot[(hf * 16 + m4 + r) * COS + px] = acc[i][hf][r];
    }
    __syncthreads();

    // scales for full groups: 32 co x up to 12 groups
    #pragma unroll
    for (int it = 0; it < 2; ++it) {
        int task = tid + it * 256;
        if (task < 384) {
            int co = ((task >> 2) * 683) >> 11;          // task/12 = (task>>2)/3
            int k = task - co * 12;
            int base = rel0s[co] + 36 * k;
            if (base < bnds[co]) {
                const float* pp = &ot[co * COS + base];
                float m = 0.f;
                #pragma unroll
                for (int i = 0; i < 9; ++i) {
                    f32x4 vv = *reinterpret_cast<const f32x4*>(pp + 4 * i);
                    m = fmaxf(m, fmaxf(fmaxf(fabsf(vv[0]), fabsf(vv[1])),
                                       fmaxf(fabsf(vv[2]), fabsf(vv[3]))));
                }
                scl[co * 12 + k] = (m > 0.f) ? scale_from_max(m) : 0.f;
            }
        }
    }
    __syncthreads();

    // quantize + store: 3584 f32x4 chunks; each chunk lies in ONE group
    // (group boundaries and chunk starts are both multiples of 4)
    float* ob = out + (size_t)(b * 32) * HWp + h0 * 224;
    #pragma unroll
    for (int j = 0; j < 14; ++j) {
        int idx = tid + j * 256;
        int co = ((idx >> 4) * 2341) >> 14;              // idx/112 = (idx>>4)/7
        int c4 = idx - co * 112;
        int px0 = c4 * 4;
        f32x4 v = *reinterpret_cast<const f32x4*>(&ot[co * COS + px0]);
        int rz = px0 - rel0s[co];
        if ((unsigned)rz < (unsigned)(bnds[co] - rel0s[co])) {   // full-group zone
            int k = (int)div36((unsigned)rz);
            float s = scl[co * 12 + k];
            if (s > 0.f) {
                float inv = inv_from_scale(s);
                #pragma unroll
                for (int e = 0; e < 4; ++e) v[e] = rintf(v[e] * inv) * s;
            } else {
                v = f32x4{0.f, 0.f, 0.f, 0.f};
            }
        }
        // else: straddle zone -> raw value, k_fixup quantizes later
        *reinterpret_cast<f32x4*>(ob + (size_t)co * HWp + px0) = v;
    }
}

// ---------- fixup: quantize the 448-boundary-straddling groups in place ----------
// Straddle groups: g mod 112 in {12,24,37,49,62,74,87,99} (8 per 112).
__global__ __launch_bounds__(256) void k_fixup(float* __restrict__ buf) {
    int i = blockIdx.x * 256 + threadIdx.x;
    if (i >= 50976) return;
    const unsigned long long SP =
        12ull | (24ull << 7) | (37ull << 14) | (49ull << 21) |
        (62ull << 28) | (74ull << 35) | (87ull << 42) | (99ull << 49);
    int g = (i >> 3) * 112 + (int)((SP >> (7 * (i & 7))) & 127ull);
    if (g >= GXN) return;
    int f4 = 9 * g;                       // 36g/4
    f32x4 v[9];
    float m = 0.f;
    #pragma unroll
    for (int k = 0; k < 9; ++k) {
        f32x4 tv = {0.f, 0.f, 0.f, 0.f};
        if ((unsigned)(f4 + k) < (unsigned)NX4)
            tv = reinterpret_cast<const f32x4*>(buf)[f4 + k];
        v[k] = tv;
        m = fmaxf(m, fmaxf(fmaxf(fabsf(tv[0]), fabsf(tv[1])),
                           fmaxf(fabsf(tv[2]), fabsf(tv[3]))));
    }
    if (m > 0.f) {
        float s = scale_from_max(m), inv = inv_from_scale(s);
        #pragma unroll
        for (int k = 0; k < 9; ++k) {
            #pragma unroll
            for (int e = 0; e < 4; ++e) v[k][e] = rintf(v[k][e] * inv) * s;
            if ((unsigned)(f4 + k) < (unsigned)NX4)
                reinterpret_cast<f32x4*>(buf)[f4 + k] = v[k];
        }
    }
}

extern "C" void kernel_launch(void* const* d_in, const int* in_sizes, int n_in,
                              void* d_out, int out_size, void* d_ws, size_t ws_size,
                              hipStream_t stream) {
    (void)in_sizes; (void)n_in; (void)out_size; (void)ws_size;
    const float* x    = (const float*)d_in[0];
    const float* w    = (const float*)d_in[1];
    const float* bias = (const float*)d_in[2];
    float* out        = (float*)d_out;

    unsigned short* xt = (unsigned short*)d_ws;   // NX bf16 NHWC (51.4 MB)
    unsigned short* wt = xt + NX;                 // 9,216 bf16

    k_quant_wt<<<1, 256, 0, stream>>>(w, wt);
    k_quant_x_fused<<<dim3(112, 16), 256, 0, stream>>>(x, xt);
    k_conv_q<<<dim3(112, 16), 256, 0, stream>>>(xt, wt, bias, out);
    k_fixup<<<200, 256, 0, stream>>>(out);        // 50,976 straddle-group slots
}

// Round 8
// 241.846 us; speedup vs baseline: 1.0860x; 1.0241x over previous
//
#include <hip/hip_runtime.h>
#include <hip/hip_bf16.h>

#define GSZ 36
static const int NX  = 16 * 32 * 224 * 224;     // 25,690,112
static const int NX4 = NX / 4;                  // 6,422,528 (NX % 4 == 0)
static const int NW  = 32 * 32 * 3 * 3;         // 9,216
static const int GXN = (NX + GSZ - 1) / GSZ;    // 713,615
static const int HWp = 224 * 224;               // 50,176 = 448 * 112

typedef short bf16x8 __attribute__((ext_vector_type(8)));
typedef float f32x4  __attribute__((ext_vector_type(4)));

// floor(n/36), exact for n < 2^31
__device__ __forceinline__ unsigned div36(unsigned n) {
    return (unsigned)(((unsigned long long)n * 954437177ull) >> 35);
}
// scale = 2^(floor(log2 m) - 7) via exponent field (m normal > 0)
__device__ __forceinline__ float scale_from_max(float m) {
    int e = (int)((__float_as_uint(m) >> 23) & 0xffu) - 127;
    return __uint_as_float((unsigned)(e + 120) << 23);
}
// 1/scale for power-of-two scale: bits = 0x7F000000 - scale_bits
__device__ __forceinline__ float inv_from_scale(float s) {
    return __uint_as_float(0x7F000000u - __float_as_uint(s));
}
__device__ __forceinline__ unsigned short f2bf(float f) {
    return (unsigned short)(__float_as_uint(f) >> 16);  // exact for BFP-8 values
}

// ---------- fused x: BFP-quantize (flat-36 groups) + NCHW->NHWC, one pass ----------
// Two ci-halves of 8 f32x4 each held in regs; chunk max -> pmax LDS (no atomics;
// groups are float4-aligned since 36 = 9*4); 224 group-tasks/half -> scales;
// quantize from regs into bf16 tile; phase D transposes to NHWC with b32 LDS
// reads (2 px per read). Block (0,0) additionally quantizes the weights
// (merged k_quant_wt) after phase D -- hidden under the other 1791 blocks.
#define TSTR 452   // bf16 tile row stride
__global__ __launch_bounds__(256, 4) void k_quant_x_fused(const float* __restrict__ x,
                                                          unsigned short* __restrict__ xt,
                                                          const float* __restrict__ w,
                                                          unsigned short* __restrict__ wt) {
    __shared__ __align__(16) unsigned short tile[32 * TSTR];  // 28,928 B
    __shared__ float pmax[16 * 128];                          //  8,192 B (one ci-half)
    __shared__ float scl[32 * 14];                            //  1,792 B

    int t = threadIdx.x;
    int b = blockIdx.y, hp = blockIdx.x;
    int F0 = (b * 32) * HWp + hp * 448;

    int c4  = t & 127;          // float4 index within the 128-float4 cover
    int ciB = t >> 7;           // 0 or 1; thread's ci_local set = {ciB + 2j}
    int gi4 = (c4 * 57) >> 9;   // c4 / 9, exact for c4 < 128

    #pragma unroll
    for (int h = 0; h < 2; ++h) {
        f32x4 v[8];
        // Phase A: coalesced group-aligned cover loads into regs; chunk max -> pmax
        #pragma unroll
        for (int j = 0; j < 8; ++j) {
            int cl = ciB + 2 * j;                            // ci_local 0..15
            int ci = h * 16 + cl;
            int F = F0 + ci * HWp;
            int r = F - 36 * (int)div36((unsigned)F);        // F % 36 (multiple of 4)
            int f4 = (int)(((unsigned)(F - r)) >> 2) + c4;   // cover float4 index
            f32x4 tv = {0.f, 0.f, 0.f, 0.f};
            if ((unsigned)f4 < (unsigned)NX4)
                tv = reinterpret_cast<const f32x4*>(x)[f4];
            v[j] = tv;
            pmax[cl * 128 + c4] = fmaxf(fmaxf(fabsf(tv[0]), fabsf(tv[1])),
                                        fmaxf(fabsf(tv[2]), fabsf(tv[3])));
        }
        __syncthreads();

        // Phase B: group max = max of 9 consecutive chunk-maxes -> scale
        if (t < 224) {                                       // 16 ci x 14 groups
            int cl = (t * 2341) >> 15;                       // t / 14, exact
            int gi = t - cl * 14;
            const float* pp = &pmax[cl * 128 + 9 * gi];
            float m = pp[0];
            #pragma unroll
            for (int i = 1; i < 9; ++i) m = fmaxf(m, pp[i]);
            scl[(h * 16 + cl) * 14 + gi] = (m > 0.f) ? scale_from_max(m) : 0.f;
        }
        __syncthreads();

        // Phase C: quantize held regs, pack bf16 into tile
        #pragma unroll
        for (int j = 0; j < 8; ++j) {
            int ci = h * 16 + ciB + 2 * j;
            int F = F0 + ci * HWp;
            int r = F - 36 * (int)div36((unsigned)F);
            int rel = 4 * c4 - r;                            // tile-relative elem offset
            if ((unsigned)rel < 448u) {
                float s = scl[ci * 14 + gi4];
                f32x4 q = v[j];
                if (s > 0.f) {
                    float inv = inv_from_scale(s);
                    #pragma unroll
                    for (int k = 0; k < 4; ++k) q[k] = rintf(q[k] * inv) * s;
                } else {
                    q = f32x4{0.f, 0.f, 0.f, 0.f};
                }
                uint2 o;
                o.x = (unsigned)f2bf(q[0]) | ((unsigned)f2bf(q[1]) << 16);
                o.y = (unsigned)f2bf(q[2]) | ((unsigned)f2bf(q[3]) << 16);
                *reinterpret_cast<uint2*>(&tile[ci * TSTR + rel]) = o;
            }
        }
        __syncthreads();   // h=0: protect pmax reuse; h=1: tile ready for phase D
    }

    // Phase D: 896 tasks of (2 px x 8 ci); 8 x ds_read_b32 each, 2 x 16B stores
    unsigned short* ob = xt + ((size_t)b * HWp + hp * 448) * 32;
    for (int j = 0; j < 4; ++j) {
        int task = t + 256 * j;
        if (task < 896) {
            int px0 = (task >> 2) << 1;            // 0,2,...,446 (even)
            int c0 = (task & 3) * 8;
            unsigned r[8];
            #pragma unroll
            for (int p = 0; p < 8; ++p)
                r[p] = *reinterpret_cast<const unsigned*>(&tile[(c0 + p) * TSTR + px0]);
            unsigned ua[4], ub[4];
            #pragma unroll
            for (int p = 0; p < 4; ++p) {
                ua[p] = (r[2*p] & 0xffffu) | (r[2*p+1] << 16);
                ub[p] = (r[2*p] >> 16)     | (r[2*p+1] & 0xffff0000u);
            }
            *reinterpret_cast<uint4*>(ob + (size_t)px0 * 32 + c0) =
                make_uint4(ua[0], ua[1], ua[2], ua[3]);
            *reinterpret_cast<uint4*>(ob + (size_t)(px0 + 1) * 32 + c0) =
                make_uint4(ub[0], ub[1], ub[2], ub[3]);
        }
    }

    // merged k_quant_wt: block (0,0) only, one group per thread
    if (b == 0 && hp == 0) {
        int base = t * GSZ;
        float vw[GSZ];
        const float4* p = reinterpret_cast<const float4*>(w + base);
        #pragma unroll
        for (int i = 0; i < 9; ++i) {
            float4 tv = p[i];
            vw[4*i+0] = tv.x; vw[4*i+1] = tv.y; vw[4*i+2] = tv.z; vw[4*i+3] = tv.w;
        }
        float m = 0.0f;
        #pragma unroll
        for (int i = 0; i < GSZ; ++i) m = fmaxf(m, fabsf(vw[i]));
        if (m > 0.0f) {
            float s = scale_from_max(m), inv = inv_from_scale(s);
            #pragma unroll
            for (int i = 0; i < GSZ; ++i) vw[i] = rintf(vw[i] * inv) * s;
        }
        #pragma unroll
        for (int i = 0; i < GSZ; ++i) {
            int f = base + i;
            int co = f / 288, rem = f - co * 288;
            int ci = rem / 9, s = rem - ci * 9;
            wt[s * 1024 + co * 32 + ci] = f2bf(vw[i]);
        }
    }
}

// ---------- fused MFMA conv + out-quant epilogue ----------
// Block = 2 full rows x 224 px x 32 co for one b. XCD-aware bijective swizzle
// (1792 = 8*224): each XCD owns contiguous (b,hpair) runs so adjacent hpairs
// (which share a 2-row staged halo) hit the same XCD's L2. Groups fully inside
// the 448-px segment are quantized here; 448-straddling groups (1/14) are
// written raw and fixed by k_fixup.
#define PXS 40
#define COS 452
__global__ __launch_bounds__(256, 2) void k_conv_q(const unsigned short* __restrict__ xt,
                                                   const unsigned short* __restrict__ wt,
                                                   const float* __restrict__ bias,
                                                   float* __restrict__ out) {
    __shared__ __align__(16) unsigned char lraw[4 * 226 * PXS * 2];  // 72,320 B union
    unsigned short* xs = reinterpret_cast<unsigned short*>(lraw);    // [4][226][PXS] bf16
    float* ot = reinterpret_cast<float*>(lraw);                      // [32][COS] f32 (57,856 B)
    __shared__ float scl[32 * 12];
    __shared__ int rel0s[32], bnds[32];

    int tid  = threadIdx.x;
    int lane = tid & 63;
    int wid  = tid >> 6;
    // XCD-aware bijective remap: flat (y-major, x fastest) -> 8 chunks of 224
    int flat = blockIdx.y * 112 + blockIdx.x;
    int nf = (flat & 7) * 224 + (flat >> 3);
    int b     = nf / 112;          // XCD k handles b in {2k, 2k+1}
    int hpair = nf - b * 112;      // contiguous hpairs within an XCD
    int h0 = hpair * 2;

    // per-co group alignment within the 448-segment
    if (tid < 32) {
        int T = (b * 32 + tid) * HWp + hpair * 448;          // 448-aligned, mult of 4
        int r36 = T - 36 * (int)div36((unsigned)T);
        int rel0 = r36 ? 36 - r36 : 0;                       // first full-group offset
        rel0s[tid] = rel0;
        bnds[tid] = rel0 + 36 * (int)div36((unsigned)(448 - rel0));  // end of full zone
    }

    // stage 4 rows (h0-1..h0+2) x 226 px x 32 ci from NHWC
    const unsigned short* xb = xt + (size_t)b * HWp * 32;
    for (int k = 0; k < 15; ++k) {
        int q = tid + k * 256;
        if (q < 3616) {                        // 4*226*4 16B-chunks
            int r = ((q >> 3) * 145) >> 14;    // (q/8)/113, exact for q<3616
            int rem = q - r * 904;
            int p = rem >> 2, ch = rem & 3;
            int gh = h0 - 1 + r, gw = p - 1;
            uint4 val = make_uint4(0u, 0u, 0u, 0u);
            if ((unsigned)gh < 224u && (unsigned)gw < 224u)
                val = *reinterpret_cast<const uint4*>(xb + ((size_t)(gh * 224 + gw)) * 32 + ch * 8);
            *reinterpret_cast<uint4*>(&xs[(r * 226 + p) * PXS + ch * 8]) = val;
        }
    }

    // weight fragments (A-operand: m=lane&15=co, k=(lane>>4)*8+j=ci)
    bf16x8 Wf[9][2];
    #pragma unroll
    for (int s = 0; s < 9; ++s)
        #pragma unroll
        for (int hf = 0; hf < 2; ++hf)
            Wf[s][hf] = *reinterpret_cast<const bf16x8*>(
                wt + s * 1024 + (hf * 16 + (lane & 15)) * 32 + (lane >> 4) * 8);

    // acc init = bias
    int m4 = (lane >> 4) << 2;
    f32x4 acc[7][2];
    {
        f32x4 b0, b1;
        #pragma unroll
        for (int r = 0; r < 4; ++r) {
            b0[r] = bias[m4 + r];
            b1[r] = bias[16 + m4 + r];
        }
        #pragma unroll
        for (int i = 0; i < 7; ++i) { acc[i][0] = b0; acc[i][1] = b1; }
    }

    __syncthreads();

    // MFMA: wave owns 7 of 28 px fragments (frag f: row=f/14, col=(f%14)*16)
    int l15 = lane & 15;
    int kchunk = (lane >> 4) << 3;
    #pragma unroll
    for (int s = 0; s < 9; ++s) {
        int kh = s / 3, kw = s - kh * 3;
        #pragma unroll
        for (int i = 0; i < 7; ++i) {
            int f = wid * 7 + i;
            int row = (f >= 14) ? 1 : 0;
            int colf = (f - 14 * row) << 4;
            bf16x8 X = *reinterpret_cast<const bf16x8*>(
                &xs[((row + kh) * 226 + colf + l15 + kw) * PXS + kchunk]);
            acc[i][0] = __builtin_amdgcn_mfma_f32_16x16x32_bf16(Wf[s][0], X, acc[i][0], 0, 0, 0);
            acc[i][1] = __builtin_amdgcn_mfma_f32_16x16x32_bf16(Wf[s][1], X, acc[i][1], 0, 0, 0);
        }
    }
    __syncthreads();   // all xs reads done; lraw becomes ot

    // acc -> ot[co][px448]   (2-way bank aliasing only)
    #pragma unroll
    for (int i = 0; i < 7; ++i) {
        int f = wid * 7 + i;
        int row = (f >= 14) ? 1 : 0;
        int px = row * 224 + ((f - 14 * row) << 4) + l15;
        #pragma unroll
        for (int hf = 0; hf < 2; ++hf)
            #pragma unroll
            for (int r = 0; r < 4; ++r)
                ot[(hf * 16 + m4 + r) * COS + px] = acc[i][hf][r];
    }
    __syncthreads();

    // scales for full groups: 32 co x up to 12 groups
    #pragma unroll
    for (int it = 0; it < 2; ++it) {
        int task = tid + it * 256;
        if (task < 384) {
            int co = ((task >> 2) * 683) >> 11;          // task/12 = (task>>2)/3
            int k = task - co * 12;
            int base = rel0s[co] + 36 * k;
            if (base < bnds[co]) {
                const float* pp = &ot[co * COS + base];
                float m = 0.f;
                #pragma unroll
                for (int i = 0; i < 9; ++i) {
                    f32x4 vv = *reinterpret_cast<const f32x4*>(pp + 4 * i);
                    m = fmaxf(m, fmaxf(fmaxf(fabsf(vv[0]), fabsf(vv[1])),
                                       fmaxf(fabsf(vv[2]), fabsf(vv[3]))));
                }
                scl[co * 12 + k] = (m > 0.f) ? scale_from_max(m) : 0.f;
            }
        }
    }
    __syncthreads();

    // quantize + store: 3584 f32x4 chunks; each chunk lies in ONE group
    float* ob = out + (size_t)(b * 32) * HWp + h0 * 224;
    #pragma unroll
    for (int j = 0; j < 14; ++j) {
        int idx = tid + j * 256;
        int co = ((idx >> 4) * 2341) >> 14;              // idx/112 = (idx>>4)/7
        int c4 = idx - co * 112;
        int px0 = c4 * 4;
        f32x4 v = *reinterpret_cast<const f32x4*>(&ot[co * COS + px0]);
        int rz = px0 - rel0s[co];
        if ((unsigned)rz < (unsigned)(bnds[co] - rel0s[co])) {   // full-group zone
            int k = (int)div36((unsigned)rz);
            float s = scl[co * 12 + k];
            if (s > 0.f) {
                float inv = inv_from_scale(s);
                #pragma unroll
                for (int e = 0; e < 4; ++e) v[e] = rintf(v[e] * inv) * s;
            } else {
                v = f32x4{0.f, 0.f, 0.f, 0.f};
            }
        }
        // else: straddle zone -> raw value, k_fixup quantizes later
        *reinterpret_cast<f32x4*>(ob + (size_t)co * HWp + px0) = v;
    }
}

// ---------- fixup: quantize the 448-boundary-straddling groups in place ----------
// Straddle groups: g mod 112 in {12,24,37,49,62,74,87,99} (8 per 112).
__global__ __launch_bounds__(256) void k_fixup(float* __restrict__ buf) {
    int i = blockIdx.x * 256 + threadIdx.x;
    if (i >= 50976) return;
    const unsigned long long SP =
        12ull | (24ull << 7) | (37ull << 14) | (49ull << 21) |
        (62ull << 28) | (74ull << 35) | (87ull << 42) | (99ull << 49);
    int g = (i >> 3) * 112 + (int)((SP >> (7 * (i & 7))) & 127ull);
    if (g >= GXN) return;
    int f4 = 9 * g;                       // 36g/4
    f32x4 v[9];
    float m = 0.f;
    #pragma unroll
    for (int k = 0; k < 9; ++k) {
        f32x4 tv = {0.f, 0.f, 0.f, 0.f};
        if ((unsigned)(f4 + k) < (unsigned)NX4)
            tv = reinterpret_cast<const f32x4*>(buf)[f4 + k];
        v[k] = tv;
        m = fmaxf(m, fmaxf(fmaxf(fabsf(tv[0]), fabsf(tv[1])),
                           fmaxf(fabsf(tv[2]), fabsf(tv[3]))));
    }
    if (m > 0.f) {
        float s = scale_from_max(m), inv = inv_from_scale(s);
        #pragma unroll
        for (int k = 0; k < 9; ++k) {
            #pragma unroll
            for (int e = 0; e < 4; ++e) v[k][e] = rintf(v[k][e] * inv) * s;
            if ((unsigned)(f4 + k) < (unsigned)NX4)
                reinterpret_cast<f32x4*>(buf)[f4 + k] = v[k];
        }
    }
}

extern "C" void kernel_launch(void* const* d_in, const int* in_sizes, int n_in,
                              void* d_out, int out_size, void* d_ws, size_t ws_size,
                              hipStream_t stream) {
    (void)in_sizes; (void)n_in; (void)out_size; (void)ws_size;
    const float* x    = (const float*)d_in[0];
    const float* w    = (const float*)d_in[1];
    const float* bias = (const float*)d_in[2];
    float* out        = (float*)d_out;

    unsigned short* xt = (unsigned short*)d_ws;   // NX bf16 NHWC (51.4 MB)
    unsigned short* wt = xt + NX;                 // 9,216 bf16

    k_quant_x_fused<<<dim3(112, 16), 256, 0, stream>>>(x, xt, w, wt);
    k_conv_q<<<dim3(112, 16), 256, 0, stream>>>(xt, wt, bias, out);
    k_fixup<<<200, 256, 0, stream>>>(out);        // 50,976 straddle-group slots
}